// Round 1
// baseline (240.558 us; speedup 1.0000x reference)
//
#include <hip/hip_runtime.h>
#include <hip/hip_bf16.h>
#include <stdint.h>

#define B_SZ 16384
#define P_SZ 8
#define D_SZ 512
#define A_SZ 64
#define K1 576    // D + A
#define H_SZ 1024
#define NSEG 64
#define MB_MAX 72               // max 256-row m-blocks after per-policy padding
#define BPAD (B_SZ + P_SZ*256)  // 18432 padded sorted-row capacity
#define PREP_BLOCKS (BPAD * 72 / 256)   // 5184
#define TRANS_BLOCKS (32 * 32 * 16)     // 16384

typedef __bf16 bf16_t;
typedef __bf16 bf16x8 __attribute__((ext_vector_type(8)));
typedef float f32x4 __attribute__((ext_vector_type(4)));

__device__ __forceinline__ void glds16(const void* g, void* l) {
    __builtin_amdgcn_global_load_lds(
        (const __attribute__((address_space(1))) unsigned*)g,
        (__attribute__((address_space(3))) unsigned*)l, 16, 0, 0);
}

// ---------------- sort prep ----------------

__global__ __launch_bounds__(256) void hist_block(const int* __restrict__ pol,
                                                  int* __restrict__ blockhist,
                                                  int* __restrict__ rowidx) {
    __shared__ int lc[P_SZ];
    int t = threadIdx.x;
    if (t < P_SZ) lc[t] = 0;
    __syncthreads();
    int gid = blockIdx.x * 256 + t;
    rowidx[gid] = -1;
    if (gid < BPAD - B_SZ) rowidx[B_SZ + gid] = -1;
    atomicAdd(&lc[pol[gid]], 1);
    __syncthreads();
    if (t < P_SZ) blockhist[blockIdx.x * P_SZ + t] = lc[t];
}

__global__ __launch_bounds__(64) void prefix_kernel(const int* __restrict__ blockhist,
                                                    int* __restrict__ counts,
                                                    int* __restrict__ cursors,
                                                    int* __restrict__ blk_p) {
    int t = threadIdx.x;
    if (t < P_SZ) {
        int s = 0;
        for (int b = 0; b < NSEG; ++b) s += blockhist[b * P_SZ + t];
        counts[t] = s;
    }
    __syncthreads();
    if (t == 0) {
        int run = 0;   // 256-aligned running offset
        for (int p = 0; p < P_SZ; ++p) {
            cursors[p] = run;
            int nb = (counts[p] + 255) >> 8;
            for (int b = 0; b < nb; ++b) blk_p[(run >> 8) + b] = p;
            run += nb * 256;
        }
        for (int b = run >> 8; b < MB_MAX; ++b) blk_p[b] = -1;
    }
}

__global__ __launch_bounds__(256) void scatter_agg(const int* __restrict__ pol,
                                                   int* __restrict__ cursors,
                                                   int* __restrict__ rowidx) {
    __shared__ int lc[P_SZ], base_s[P_SZ];
    int t = threadIdx.x;
    if (t < P_SZ) lc[t] = 0;
    __syncthreads();
    int i = blockIdx.x * 256 + t;
    int p = pol[i];
    int lpos = atomicAdd(&lc[p], 1);
    __syncthreads();
    if (t < P_SZ) base_s[t] = atomicAdd(&cursors[t], lc[t]);
    __syncthreads();
    rowidx[base_s[p] + lpos] = i;
}

// ---------------- prep_all: fused x-gather/convert + weight transposes ----------------

__global__ __launch_bounds__(256) void prep_all(const float* __restrict__ latents,
                                                const float* __restrict__ actions,
                                                const int* __restrict__ rowidx,
                                                const float* __restrict__ W1,
                                                const float* __restrict__ W2,
                                                bf16_t* __restrict__ xs,
                                                bf16_t* __restrict__ w1t,
                                                bf16_t* __restrict__ w2t) {
    int bx = blockIdx.x;
    int tid = threadIdx.x;
    if (bx < PREP_BLOCKS) {
        int idx = bx * 256 + tid;
        int s = idx / 72;
        int col = (idx - s * 72) * 8;
        int g = rowidx[s];
        bf16x8 o;
        if (g < 0) {
            o = (bf16x8){0,0,0,0,0,0,0,0};
        } else {
            const float* src;
            if (col < D_SZ) src = latents + (size_t)g * D_SZ + col;
            else            src = actions + (size_t)g * A_SZ + (col - D_SZ);
            f32x4 v0 = *(const f32x4*)src;
            f32x4 v1 = *(const f32x4*)(src + 4);
            o[0] = (bf16_t)v0[0]; o[1] = (bf16_t)v0[1]; o[2] = (bf16_t)v0[2]; o[3] = (bf16_t)v0[3];
            o[4] = (bf16_t)v1[0]; o[5] = (bf16_t)v1[1]; o[6] = (bf16_t)v1[2]; o[7] = (bf16_t)v1[3];
        }
        *(bf16x8*)(xs + (size_t)s * K1 + col) = o;
        return;
    }
    int tz = bx - PREP_BLOCKS;        // 0..16383
    int z = tz >> 10;                 // 0..15
    int rem = tz & 1023;
    int k0 = (rem & 31) * 32, n0 = (rem >> 5) * 32;
    int K = (z < P_SZ) ? K1 : H_SZ;
    int N = (z < P_SZ) ? H_SZ : D_SZ;
    if (k0 >= K || n0 >= N) return;
    int p = z & 7;
    const float* Wp = ((z < P_SZ) ? W1 : W2) + (size_t)p * K * N;
    bf16_t* WTp = ((z < P_SZ) ? w1t : w2t) + (size_t)p * N * K;
    __shared__ float ls[32][33];
    {   // vectorized tile load: one f32x4 per thread covers the 32x32 tile
        int kk = tid >> 3, nn = (tid & 7) * 4;
        f32x4 v = *(const f32x4*)&Wp[(size_t)(k0 + kk) * N + n0 + nn];
        ls[kk][nn]     = v[0];
        ls[kk][nn + 1] = v[1];
        ls[kk][nn + 2] = v[2];
        ls[kk][nn + 3] = v[3];
    }
    __syncthreads();
#pragma unroll
    for (int e = 0; e < 2; ++e) {
        int idx = e * 256 + tid;
        int nn = idx >> 4, kp = (idx & 15) * 2;
        union { bf16_t h[2]; unsigned u; } pk;
        pk.h[0] = (bf16_t)ls[kp][nn];
        pk.h[1] = (bf16_t)ls[kp + 1][nn];
        *(unsigned*)&WTp[(size_t)(n0 + nn) * K + k0 + kp] = pk.u;
    }
}

// ---------------- GEMMs: BM=256, 4 waves (pure m-split) ----------------------------
// T3 minimal 2-phase pipeline: double-buffered LDS, stage(t+1) issued BEFORE the
// ds_read+MFMA of tile t, ONE barrier/iter (compiler's implicit vmcnt(0) drain then
// waits on loads issued a full compute-phase earlier). XOR chunk swizzle unchanged
// (stored pos kc holds logical kc^((row>>1)&3)) -> 0 bank conflicts (measured).
// gemm1: 2x24KB LDS -> 3 blocks/CU (576-block grid fully co-resident, no tail).
// gemm2: 2x20KB LDS -> 4 blocks/CU.

__global__ __launch_bounds__(256, 3) void gemm1_kernel(
    const bf16_t* __restrict__ xs, const bf16_t* __restrict__ w1t,
    const float* __restrict__ b1, const int* __restrict__ blk_p,
    bf16_t* __restrict__ h) {

    const int p = blk_p[blockIdx.x];
    if (p < 0) return;
    const int m0 = blockIdx.x * 256;
    const int n0 = blockIdx.y * 128;

    constexpr int AE = 256 * 32;   // elems per A buffer (16 KB)
    constexpr int BE = 128 * 32;   // elems per B buffer (8 KB)
    __shared__ __align__(16) bf16_t As[2 * AE];
    __shared__ __align__(16) bf16_t Bs[2 * BE];

    const int tid = threadIdx.x;
    const int wave = tid >> 6, lane = tid & 63;

    // A: 1024 chunks, 16 glds slots; wave handles slots wave*4+i
    const bf16_t* a_src[4]; bf16_t* a_dst[4];
#pragma unroll
    for (int i = 0; i < 4; ++i) {
        int c = (wave * 4 + i) * 64 + lane;
        int r = c >> 2;
        int kl = (c & 3) ^ ((r >> 1) & 3);
        a_src[i] = xs + (size_t)(m0 + r) * K1 + kl * 8;
        a_dst[i] = As + c * 8;
    }
    // B: 512 chunks, 8 slots; wave handles slots wave*2+i
    const bf16_t* b_src[2]; bf16_t* b_dst[2];
#pragma unroll
    for (int i = 0; i < 2; ++i) {
        int c = (wave * 2 + i) * 64 + lane;
        int r = c >> 2;
        int kl = (c & 3) ^ ((r >> 1) & 3);
        b_src[i] = w1t + ((size_t)p * H_SZ + n0 + r) * K1 + kl * 8;
        b_dst[i] = Bs + c * 8;
    }

    // prologue: stage tile 0 into buffer 0
#pragma unroll
    for (int i = 0; i < 4; ++i) glds16(a_src[i], a_dst[i]);
#pragma unroll
    for (int i = 0; i < 2; ++i) glds16(b_src[i], b_dst[i]);

    const int l16 = lane & 15, qd = lane >> 4;
    const int swz = (l16 >> 1) & 3;
    int aoff[4], boff[8];
#pragma unroll
    for (int i = 0; i < 4; ++i) aoff[i] = (wave * 64 + i * 16 + l16) * 32 + ((qd ^ swz) * 8);
#pragma unroll
    for (int j = 0; j < 8; ++j) boff[j] = (j * 16 + l16) * 32 + ((qd ^ swz) * 8);

    f32x4 acc[4][8];
#pragma unroll
    for (int i = 0; i < 4; ++i)
#pragma unroll
        for (int j = 0; j < 8; ++j)
            acc[i][j] = (f32x4){0.f, 0.f, 0.f, 0.f};

    constexpr int NT = K1 / 32;    // 18
    for (int t = 0; t < NT; ++t) {
        __syncthreads();           // tile t resident (implicit vmcnt(0) drain)
        const int nxt = t + 1;
        if (nxt < NT) {            // issue next-tile loads before compute
            const int po = (nxt & 1) ? AE : 0;
            const int pb = (nxt & 1) ? BE : 0;
#pragma unroll
            for (int i = 0; i < 4; ++i) glds16(a_src[i] + nxt * 32, a_dst[i] + po);
#pragma unroll
            for (int i = 0; i < 2; ++i) glds16(b_src[i] + nxt * 32, b_dst[i] + pb);
        }
        const int co = (t & 1) ? AE : 0;
        const int cb = (t & 1) ? BE : 0;
        bf16x8 af[4], bfv[8];
#pragma unroll
        for (int i = 0; i < 4; ++i) af[i] = *(const bf16x8*)(As + co + aoff[i]);
#pragma unroll
        for (int j = 0; j < 8; ++j) bfv[j] = *(const bf16x8*)(Bs + cb + boff[j]);
#pragma unroll
        for (int i = 0; i < 4; ++i)
#pragma unroll
            for (int j = 0; j < 8; ++j)
                acc[i][j] = __builtin_amdgcn_mfma_f32_16x16x32_bf16(af[i], bfv[j], acc[i][j], 0, 0, 0);
    }

    // epilogue: bias + relu -> h (padded sorted layout)
#pragma unroll
    for (int i = 0; i < 4; ++i) {
#pragma unroll
        for (int r = 0; r < 4; ++r) {
            int ml = wave * 64 + i * 16 + qd * 4 + r;   // C/D: row = quad*4 + reg
            size_t row = (size_t)(m0 + ml);
#pragma unroll
            for (int j = 0; j < 8; ++j) {
                int n = n0 + j * 16 + l16;              // C/D: col = lane&15
                float v = acc[i][j][r] + b1[p * H_SZ + n];
                h[row * H_SZ + n] = (bf16_t)fmaxf(v, 0.f);
            }
        }
    }
}

__global__ __launch_bounds__(256, 4) void gemm2_kernel(
    const bf16_t* __restrict__ h, const bf16_t* __restrict__ w2t,
    const float* __restrict__ b2, const int* __restrict__ blk_p,
    const int* __restrict__ rowidx, float* __restrict__ out) {

    const int p = blk_p[blockIdx.x];
    if (p < 0) return;
    const int m0 = blockIdx.x * 256;
    const int n0 = blockIdx.y * 64;

    constexpr int AE = 256 * 32;   // 16 KB
    constexpr int BE = 64 * 32;    // 4 KB
    __shared__ __align__(16) bf16_t As[2 * AE];
    __shared__ __align__(16) bf16_t Bs[2 * BE];

    const int tid = threadIdx.x;
    const int wave = tid >> 6, lane = tid & 63;

    const bf16_t* a_src[4]; bf16_t* a_dst[4];
#pragma unroll
    for (int i = 0; i < 4; ++i) {
        int c = (wave * 4 + i) * 64 + lane;
        int r = c >> 2;
        int kl = (c & 3) ^ ((r >> 1) & 3);
        a_src[i] = h + (size_t)(m0 + r) * H_SZ + kl * 8;
        a_dst[i] = As + c * 8;
    }
    // B: 256 chunks, 4 slots; wave handles slot `wave`
    const bf16_t* b_src0; bf16_t* b_dst0;
    {
        int c = wave * 64 + lane;
        int r = c >> 2;
        int kl = (c & 3) ^ ((r >> 1) & 3);
        b_src0 = w2t + ((size_t)p * D_SZ + n0 + r) * H_SZ + kl * 8;
        b_dst0 = Bs + c * 8;
    }

    // prologue: stage tile 0 into buffer 0
#pragma unroll
    for (int i = 0; i < 4; ++i) glds16(a_src[i], a_dst[i]);
    glds16(b_src0, b_dst0);

    const int l16 = lane & 15, qd = lane >> 4;
    const int swz = (l16 >> 1) & 3;
    int aoff[4], boff[4];
#pragma unroll
    for (int i = 0; i < 4; ++i) aoff[i] = (wave * 64 + i * 16 + l16) * 32 + ((qd ^ swz) * 8);
#pragma unroll
    for (int j = 0; j < 4; ++j) boff[j] = (j * 16 + l16) * 32 + ((qd ^ swz) * 8);

    f32x4 acc[4][4];
#pragma unroll
    for (int i = 0; i < 4; ++i)
#pragma unroll
        for (int j = 0; j < 4; ++j)
            acc[i][j] = (f32x4){0.f, 0.f, 0.f, 0.f};

    constexpr int NT = H_SZ / 32;  // 32
    for (int t = 0; t < NT; ++t) {
        __syncthreads();           // tile t resident (implicit vmcnt(0) drain)
        const int nxt = t + 1;
        if (nxt < NT) {
            const int po = (nxt & 1) ? AE : 0;
            const int pb = (nxt & 1) ? BE : 0;
#pragma unroll
            for (int i = 0; i < 4; ++i) glds16(a_src[i] + nxt * 32, a_dst[i] + po);
            glds16(b_src0 + nxt * 32, b_dst0 + pb);
        }
        const int co = (t & 1) ? AE : 0;
        const int cb = (t & 1) ? BE : 0;
        bf16x8 af[4], bfv[4];
#pragma unroll
        for (int i = 0; i < 4; ++i) af[i] = *(const bf16x8*)(As + co + aoff[i]);
#pragma unroll
        for (int j = 0; j < 4; ++j) bfv[j] = *(const bf16x8*)(Bs + cb + boff[j]);
#pragma unroll
        for (int i = 0; i < 4; ++i)
#pragma unroll
            for (int j = 0; j < 4; ++j)
                acc[i][j] = __builtin_amdgcn_mfma_f32_16x16x32_bf16(af[i], bfv[j], acc[i][j], 0, 0, 0);
    }

    // epilogue: bias, scatter to original rows; pad rows masked
#pragma unroll
    for (int i = 0; i < 4; ++i) {
#pragma unroll
        for (int r = 0; r < 4; ++r) {
            int ml = wave * 64 + i * 16 + qd * 4 + r;
            int g = rowidx[m0 + ml];
            if (g >= 0) {
                size_t orow = (size_t)g * D_SZ;
#pragma unroll
                for (int j = 0; j < 4; ++j) {
                    int n = n0 + j * 16 + l16;
                    out[orow + n] = acc[i][j][r] + b2[p * D_SZ + n];
                }
            }
        }
    }
}

// ---------------- launch ----------------

extern "C" void kernel_launch(void* const* d_in, const int* in_sizes, int n_in,
                              void* d_out, int out_size, void* d_ws, size_t ws_size,
                              hipStream_t stream) {
    const float* latents = (const float*)d_in[0];
    const float* actions = (const float*)d_in[1];
    const int*   pol     = (const int*)d_in[2];
    const float* W1      = (const float*)d_in[3];
    const float* b1      = (const float*)d_in[4];
    const float* W2      = (const float*)d_in[5];
    const float* b2      = (const float*)d_in[6];
    float* out = (float*)d_out;

    char* ws = (char*)d_ws;
    int* counts    = (int*)ws;
    int* cursors   = counts + P_SZ;
    int* blk_p     = cursors + P_SZ;
    int* blockhist = blk_p + MB_MAX;
    int* rowidx    = blockhist + NSEG * P_SZ;
    size_t pos = ((size_t)(2 * P_SZ + MB_MAX + NSEG * P_SZ + BPAD) * sizeof(int) + 255) & ~(size_t)255;
    bf16_t* xs  = (bf16_t*)(ws + pos);  pos += (size_t)BPAD * K1 * 2;
    bf16_t* hbuf= (bf16_t*)(ws + pos);  pos += (size_t)BPAD * H_SZ * 2;
    bf16_t* w1t = (bf16_t*)(ws + pos);  pos += (size_t)P_SZ * H_SZ * K1 * 2;
    bf16_t* w2t = (bf16_t*)(ws + pos);  pos += (size_t)P_SZ * D_SZ * H_SZ * 2;

    hist_block<<<NSEG, 256, 0, stream>>>(pol, blockhist, rowidx);
    prefix_kernel<<<1, 64, 0, stream>>>(blockhist, counts, cursors, blk_p);
    scatter_agg<<<NSEG, 256, 0, stream>>>(pol, cursors, rowidx);
    prep_all<<<PREP_BLOCKS + TRANS_BLOCKS, 256, 0, stream>>>(
        latents, actions, rowidx, W1, W2, xs, w1t, w2t);
    gemm1_kernel<<<dim3(MB_MAX, H_SZ / 128), 256, 0, stream>>>(xs, w1t, b1, blk_p, hbuf);
    gemm2_kernel<<<dim3(MB_MAX, D_SZ / 64), 256, 0, stream>>>(hbuf, w2t, b2, blk_p, rowidx, out);
}

// Round 2
// 234.080 us; speedup vs baseline: 1.0277x; 1.0277x over previous
//
#include <hip/hip_runtime.h>
#include <hip/hip_bf16.h>
#include <stdint.h>

#define B_SZ 16384
#define P_SZ 8
#define D_SZ 512
#define A_SZ 64
#define K1 576    // D + A
#define H_SZ 1024
#define NSEG 64
#define MB_MAX 72               // max 256-row m-blocks after per-policy padding
#define BPAD (B_SZ + P_SZ*256)  // 18432 padded sorted-row capacity
#define PREP_BLOCKS (BPAD * 72 / 256)   // 5184
#define TRANS_BLOCKS (32 * 32 * 16)     // 16384

typedef __bf16 bf16_t;
typedef __bf16 bf16x8 __attribute__((ext_vector_type(8)));
typedef float f32x4 __attribute__((ext_vector_type(4)));

__device__ __forceinline__ void glds16(const void* g, void* l) {
    __builtin_amdgcn_global_load_lds(
        (const __attribute__((address_space(1))) unsigned*)g,
        (__attribute__((address_space(3))) unsigned*)l, 16, 0, 0);
}

// ---------------- sort prep ----------------

__global__ __launch_bounds__(256) void hist_block(const int* __restrict__ pol,
                                                  int* __restrict__ blockhist,
                                                  int* __restrict__ rowidx) {
    __shared__ int lc[P_SZ];
    int t = threadIdx.x;
    if (t < P_SZ) lc[t] = 0;
    __syncthreads();
    int gid = blockIdx.x * 256 + t;
    rowidx[gid] = -1;
    if (gid < BPAD - B_SZ) rowidx[B_SZ + gid] = -1;
    atomicAdd(&lc[pol[gid]], 1);
    __syncthreads();
    if (t < P_SZ) blockhist[blockIdx.x * P_SZ + t] = lc[t];
}

__global__ __launch_bounds__(64) void prefix_kernel(const int* __restrict__ blockhist,
                                                    int* __restrict__ counts,
                                                    int* __restrict__ cursors,
                                                    int* __restrict__ blk_p) {
    int t = threadIdx.x;
    if (t < P_SZ) {
        int s = 0;
        for (int b = 0; b < NSEG; ++b) s += blockhist[b * P_SZ + t];
        counts[t] = s;
    }
    __syncthreads();
    if (t == 0) {
        int run = 0;   // 256-aligned running offset
        for (int p = 0; p < P_SZ; ++p) {
            cursors[p] = run;
            int nb = (counts[p] + 255) >> 8;
            for (int b = 0; b < nb; ++b) blk_p[(run >> 8) + b] = p;
            run += nb * 256;
        }
        for (int b = run >> 8; b < MB_MAX; ++b) blk_p[b] = -1;
    }
}

__global__ __launch_bounds__(256) void scatter_agg(const int* __restrict__ pol,
                                                   int* __restrict__ cursors,
                                                   int* __restrict__ rowidx) {
    __shared__ int lc[P_SZ], base_s[P_SZ];
    int t = threadIdx.x;
    if (t < P_SZ) lc[t] = 0;
    __syncthreads();
    int i = blockIdx.x * 256 + t;
    int p = pol[i];
    int lpos = atomicAdd(&lc[p], 1);
    __syncthreads();
    if (t < P_SZ) base_s[t] = atomicAdd(&cursors[t], lc[t]);
    __syncthreads();
    rowidx[base_s[p] + lpos] = i;
}

// ---------------- prep_all: fused x-gather/convert + weight transposes ----------------

__global__ __launch_bounds__(256) void prep_all(const float* __restrict__ latents,
                                                const float* __restrict__ actions,
                                                const int* __restrict__ rowidx,
                                                const float* __restrict__ W1,
                                                const float* __restrict__ W2,
                                                bf16_t* __restrict__ xs,
                                                bf16_t* __restrict__ w1t,
                                                bf16_t* __restrict__ w2t) {
    int bx = blockIdx.x;
    int tid = threadIdx.x;
    if (bx < PREP_BLOCKS) {
        int idx = bx * 256 + tid;
        int s = idx / 72;
        int col = (idx - s * 72) * 8;
        int g = rowidx[s];
        bf16x8 o;
        if (g < 0) {
            o = (bf16x8){0,0,0,0,0,0,0,0};
        } else {
            const float* src;
            if (col < D_SZ) src = latents + (size_t)g * D_SZ + col;
            else            src = actions + (size_t)g * A_SZ + (col - D_SZ);
            f32x4 v0 = *(const f32x4*)src;
            f32x4 v1 = *(const f32x4*)(src + 4);
            o[0] = (bf16_t)v0[0]; o[1] = (bf16_t)v0[1]; o[2] = (bf16_t)v0[2]; o[3] = (bf16_t)v0[3];
            o[4] = (bf16_t)v1[0]; o[5] = (bf16_t)v1[1]; o[6] = (bf16_t)v1[2]; o[7] = (bf16_t)v1[3];
        }
        *(bf16x8*)(xs + (size_t)s * K1 + col) = o;
        return;
    }
    int tz = bx - PREP_BLOCKS;        // 0..16383
    int z = tz >> 10;                 // 0..15
    int rem = tz & 1023;
    int k0 = (rem & 31) * 32, n0 = (rem >> 5) * 32;
    int K = (z < P_SZ) ? K1 : H_SZ;
    int N = (z < P_SZ) ? H_SZ : D_SZ;
    if (k0 >= K || n0 >= N) return;
    int p = z & 7;
    const float* Wp = ((z < P_SZ) ? W1 : W2) + (size_t)p * K * N;
    bf16_t* WTp = ((z < P_SZ) ? w1t : w2t) + (size_t)p * N * K;
    __shared__ float ls[32][33];
    {   // vectorized tile load: one f32x4 per thread covers the 32x32 tile
        int kk = tid >> 3, nn = (tid & 7) * 4;
        f32x4 v = *(const f32x4*)&Wp[(size_t)(k0 + kk) * N + n0 + nn];
        ls[kk][nn]     = v[0];
        ls[kk][nn + 1] = v[1];
        ls[kk][nn + 2] = v[2];
        ls[kk][nn + 3] = v[3];
    }
    __syncthreads();
#pragma unroll
    for (int e = 0; e < 2; ++e) {
        int idx = e * 256 + tid;
        int nn = idx >> 4, kp = (idx & 15) * 2;
        union { bf16_t h[2]; unsigned u; } pk;
        pk.h[0] = (bf16_t)ls[kp][nn];
        pk.h[1] = (bf16_t)ls[kp + 1][nn];
        *(unsigned*)&WTp[(size_t)(n0 + nn) * K + k0 + kp] = pk.u;
    }
}

// ---------------- GEMMs: BM=256, 4 waves (pure m-split) -----------------------------
// T4 depth-2 pipeline: 3 LDS buffers, counted vmcnt (never 0 in-loop), raw s_barrier.
// Per iter: wait vmcnt(G) [tile t landed; t+1 in flight] -> barrier -> issue stage(t+2)
// -> ds_read(t) -> MFMA. Loads get two compute phases of latency cover.
// launch_bounds(256,2): register budget 256 -> NO spills (round-1 lesson: (256,3)
// forced ~230 regs into a 170 budget -> +13MB scratch writes, +25us).
// XOR chunk swizzle unchanged (0 bank conflicts measured).

__global__ __launch_bounds__(256, 2) void gemm1_kernel(
    const bf16_t* __restrict__ xs, const bf16_t* __restrict__ w1t,
    const float* __restrict__ b1, const int* __restrict__ blk_p,
    bf16_t* __restrict__ h) {

    const int p = blk_p[blockIdx.x];
    if (p < 0) return;
    const int m0 = blockIdx.x * 256;
    const int n0 = blockIdx.y * 128;

    constexpr int AE = 256 * 32;   // elems per A buffer (16 KB)
    constexpr int BE = 128 * 32;   // elems per B buffer (8 KB)
    __shared__ __align__(16) bf16_t As[3 * AE];   // 48 KB
    __shared__ __align__(16) bf16_t Bs[3 * BE];   // 24 KB

    const int tid = threadIdx.x;
    const int wave = tid >> 6, lane = tid & 63;

    // A: 1024 chunks, 16 glds slots; wave handles slots wave*4+i
    const bf16_t* a_src[4]; int a_slot[4];
#pragma unroll
    for (int i = 0; i < 4; ++i) {
        int c = (wave * 4 + i) * 64 + lane;
        int r = c >> 2;
        int kl = (c & 3) ^ ((r >> 1) & 3);
        a_src[i] = xs + (size_t)(m0 + r) * K1 + kl * 8;
        a_slot[i] = c * 8;
    }
    // B: 512 chunks, 8 slots; wave handles slots wave*2+i
    const bf16_t* b_src[2]; int b_slot[2];
#pragma unroll
    for (int i = 0; i < 2; ++i) {
        int c = (wave * 2 + i) * 64 + lane;
        int r = c >> 2;
        int kl = (c & 3) ^ ((r >> 1) & 3);
        b_src[i] = w1t + ((size_t)p * H_SZ + n0 + r) * K1 + kl * 8;
        b_slot[i] = c * 8;
    }

    auto stage = [&](int kt, int oA, int oB) {
#pragma unroll
        for (int i = 0; i < 4; ++i) glds16(a_src[i] + kt, As + oA + a_slot[i]);
#pragma unroll
        for (int i = 0; i < 2; ++i) glds16(b_src[i] + kt, Bs + oB + b_slot[i]);
    };

    // prologue: tiles 0 and 1 in flight (12 outstanding glds/thread)
    stage(0, 0, 0);
    stage(32, AE, BE);

    const int l16 = lane & 15, qd = lane >> 4;
    const int swz = (l16 >> 1) & 3;
    int aoff[4], boff[8];
#pragma unroll
    for (int i = 0; i < 4; ++i) aoff[i] = (wave * 64 + i * 16 + l16) * 32 + ((qd ^ swz) * 8);
#pragma unroll
    for (int j = 0; j < 8; ++j) boff[j] = (j * 16 + l16) * 32 + ((qd ^ swz) * 8);

    f32x4 acc[4][8];
#pragma unroll
    for (int i = 0; i < 4; ++i)
#pragma unroll
        for (int j = 0; j < 8; ++j)
            acc[i][j] = (f32x4){0.f, 0.f, 0.f, 0.f};

    int cA0 = 0, cA1 = AE, cA2 = 2 * AE;   // rotating buffer offsets: t, t+1, t+2
    int cB0 = 0, cB1 = BE, cB2 = 2 * BE;

    constexpr int NT = K1 / 32;    // 18
    for (int t = 0; t < NT; ++t) {
        // tile t's 6 loads done; tile t+1's 6 may remain in flight
        if (t < NT - 1) asm volatile("s_waitcnt vmcnt(6)" ::: "memory");
        else            asm volatile("s_waitcnt vmcnt(0)" ::: "memory");
        __builtin_amdgcn_s_barrier();
        if (t + 2 < NT) stage((t + 2) * 32, cA2, cB2);
        bf16x8 af[4], bfv[8];
#pragma unroll
        for (int i = 0; i < 4; ++i) af[i] = *(const bf16x8*)(As + cA0 + aoff[i]);
#pragma unroll
        for (int j = 0; j < 8; ++j) bfv[j] = *(const bf16x8*)(Bs + cB0 + boff[j]);
#pragma unroll
        for (int i = 0; i < 4; ++i)
#pragma unroll
            for (int j = 0; j < 8; ++j)
                acc[i][j] = __builtin_amdgcn_mfma_f32_16x16x32_bf16(af[i], bfv[j], acc[i][j], 0, 0, 0);
        int ta = cA0; cA0 = cA1; cA1 = cA2; cA2 = ta;
        int tb = cB0; cB0 = cB1; cB1 = cB2; cB2 = tb;
    }

    // epilogue: bias + relu -> h (padded sorted layout)
#pragma unroll
    for (int i = 0; i < 4; ++i) {
#pragma unroll
        for (int r = 0; r < 4; ++r) {
            int ml = wave * 64 + i * 16 + qd * 4 + r;   // C/D: row = quad*4 + reg
            size_t row = (size_t)(m0 + ml);
#pragma unroll
            for (int j = 0; j < 8; ++j) {
                int n = n0 + j * 16 + l16;              // C/D: col = lane&15
                float v = acc[i][j][r] + b1[p * H_SZ + n];
                h[row * H_SZ + n] = (bf16_t)fmaxf(v, 0.f);
            }
        }
    }
}

__global__ __launch_bounds__(256, 2) void gemm2_kernel(
    const bf16_t* __restrict__ h, const bf16_t* __restrict__ w2t,
    const float* __restrict__ b2, const int* __restrict__ blk_p,
    const int* __restrict__ rowidx, float* __restrict__ out) {

    const int p = blk_p[blockIdx.x];
    if (p < 0) return;
    const int m0 = blockIdx.x * 256;
    const int n0 = blockIdx.y * 64;

    constexpr int AE = 256 * 32;   // 16 KB
    constexpr int BE = 64 * 32;    // 4 KB
    __shared__ __align__(16) bf16_t As[3 * AE];   // 48 KB
    __shared__ __align__(16) bf16_t Bs[3 * BE];   // 12 KB

    const int tid = threadIdx.x;
    const int wave = tid >> 6, lane = tid & 63;

    const bf16_t* a_src[4]; int a_slot[4];
#pragma unroll
    for (int i = 0; i < 4; ++i) {
        int c = (wave * 4 + i) * 64 + lane;
        int r = c >> 2;
        int kl = (c & 3) ^ ((r >> 1) & 3);
        a_src[i] = h + (size_t)(m0 + r) * H_SZ + kl * 8;
        a_slot[i] = c * 8;
    }
    // B: 256 chunks, 4 slots; wave handles slot `wave`
    const bf16_t* b_src0; int b_slot0;
    {
        int c = wave * 64 + lane;
        int r = c >> 2;
        int kl = (c & 3) ^ ((r >> 1) & 3);
        b_src0 = w2t + ((size_t)p * D_SZ + n0 + r) * H_SZ + kl * 8;
        b_slot0 = c * 8;
    }

    auto stage = [&](int kt, int oA, int oB) {
#pragma unroll
        for (int i = 0; i < 4; ++i) glds16(a_src[i] + kt, As + oA + a_slot[i]);
        glds16(b_src0 + kt, Bs + oB + b_slot0);
    };

    // prologue: tiles 0 and 1 in flight (10 outstanding glds/thread)
    stage(0, 0, 0);
    stage(32, AE, BE);

    const int l16 = lane & 15, qd = lane >> 4;
    const int swz = (l16 >> 1) & 3;
    int aoff[4], boff[4];
#pragma unroll
    for (int i = 0; i < 4; ++i) aoff[i] = (wave * 64 + i * 16 + l16) * 32 + ((qd ^ swz) * 8);
#pragma unroll
    for (int j = 0; j < 4; ++j) boff[j] = (j * 16 + l16) * 32 + ((qd ^ swz) * 8);

    f32x4 acc[4][4];
#pragma unroll
    for (int i = 0; i < 4; ++i)
#pragma unroll
        for (int j = 0; j < 4; ++j)
            acc[i][j] = (f32x4){0.f, 0.f, 0.f, 0.f};

    int cA0 = 0, cA1 = AE, cA2 = 2 * AE;
    int cB0 = 0, cB1 = BE, cB2 = 2 * BE;

    constexpr int NT = H_SZ / 32;  // 32
    for (int t = 0; t < NT; ++t) {
        if (t < NT - 1) asm volatile("s_waitcnt vmcnt(5)" ::: "memory");
        else            asm volatile("s_waitcnt vmcnt(0)" ::: "memory");
        __builtin_amdgcn_s_barrier();
        if (t + 2 < NT) stage((t + 2) * 32, cA2, cB2);
        bf16x8 af[4], bfv[4];
#pragma unroll
        for (int i = 0; i < 4; ++i) af[i] = *(const bf16x8*)(As + cA0 + aoff[i]);
#pragma unroll
        for (int j = 0; j < 4; ++j) bfv[j] = *(const bf16x8*)(Bs + cB0 + boff[j]);
#pragma unroll
        for (int i = 0; i < 4; ++i)
#pragma unroll
            for (int j = 0; j < 4; ++j)
                acc[i][j] = __builtin_amdgcn_mfma_f32_16x16x32_bf16(af[i], bfv[j], acc[i][j], 0, 0, 0);
        int ta = cA0; cA0 = cA1; cA1 = cA2; cA2 = ta;
        int tb = cB0; cB0 = cB1; cB1 = cB2; cB2 = tb;
    }

    // epilogue: bias, scatter to original rows; pad rows masked
#pragma unroll
    for (int i = 0; i < 4; ++i) {
#pragma unroll
        for (int r = 0; r < 4; ++r) {
            int ml = wave * 64 + i * 16 + qd * 4 + r;
            int g = rowidx[m0 + ml];
            if (g >= 0) {
                size_t orow = (size_t)g * D_SZ;
#pragma unroll
                for (int j = 0; j < 4; ++j) {
                    int n = n0 + j * 16 + l16;
                    out[orow + n] = acc[i][j][r] + b2[p * D_SZ + n];
                }
            }
        }
    }
}

// ---------------- launch ----------------

extern "C" void kernel_launch(void* const* d_in, const int* in_sizes, int n_in,
                              void* d_out, int out_size, void* d_ws, size_t ws_size,
                              hipStream_t stream) {
    const float* latents = (const float*)d_in[0];
    const float* actions = (const float*)d_in[1];
    const int*   pol     = (const int*)d_in[2];
    const float* W1      = (const float*)d_in[3];
    const float* b1      = (const float*)d_in[4];
    const float* W2      = (const float*)d_in[5];
    const float* b2      = (const float*)d_in[6];
    float* out = (float*)d_out;

    char* ws = (char*)d_ws;
    int* counts    = (int*)ws;
    int* cursors   = counts + P_SZ;
    int* blk_p     = cursors + P_SZ;
    int* blockhist = blk_p + MB_MAX;
    int* rowidx    = blockhist + NSEG * P_SZ;
    size_t pos = ((size_t)(2 * P_SZ + MB_MAX + NSEG * P_SZ + BPAD) * sizeof(int) + 255) & ~(size_t)255;
    bf16_t* xs  = (bf16_t*)(ws + pos);  pos += (size_t)BPAD * K1 * 2;
    bf16_t* hbuf= (bf16_t*)(ws + pos);  pos += (size_t)BPAD * H_SZ * 2;
    bf16_t* w1t = (bf16_t*)(ws + pos);  pos += (size_t)P_SZ * H_SZ * K1 * 2;
    bf16_t* w2t = (bf16_t*)(ws + pos);  pos += (size_t)P_SZ * D_SZ * H_SZ * 2;

    hist_block<<<NSEG, 256, 0, stream>>>(pol, blockhist, rowidx);
    prefix_kernel<<<1, 64, 0, stream>>>(blockhist, counts, cursors, blk_p);
    scatter_agg<<<NSEG, 256, 0, stream>>>(pol, cursors, rowidx);
    prep_all<<<PREP_BLOCKS + TRANS_BLOCKS, 256, 0, stream>>>(
        latents, actions, rowidx, W1, W2, xs, w1t, w2t);
    gemm1_kernel<<<dim3(MB_MAX, H_SZ / 128), 256, 0, stream>>>(xs, w1t, b1, blk_p, hbuf);
    gemm2_kernel<<<dim3(MB_MAX, D_SZ / 64), 256, 0, stream>>>(hbuf, w2t, b2, blk_p, rowidx, out);
}

// Round 3
// 209.370 us; speedup vs baseline: 1.1490x; 1.1180x over previous
//
#include <hip/hip_runtime.h>
#include <hip/hip_bf16.h>
#include <stdint.h>

#define B_SZ 16384
#define P_SZ 8
#define D_SZ 512
#define A_SZ 64
#define K1 576    // D + A
#define H_SZ 1024
#define NSEG 64
#define MB_MAX 72               // max 256-row m-blocks after per-policy padding
#define BPAD (B_SZ + P_SZ*256)  // 18432 padded sorted-row capacity
#define PREP_BLOCKS (BPAD * 72 / 256)   // 5184
#define TRANS_BLOCKS (32 * 32 * 16)     // 16384

typedef __bf16 bf16_t;
typedef __bf16 bf16x8 __attribute__((ext_vector_type(8)));
typedef float f32x4 __attribute__((ext_vector_type(4)));

__device__ __forceinline__ void glds16(const void* g, void* l) {
    __builtin_amdgcn_global_load_lds(
        (const __attribute__((address_space(1))) unsigned*)g,
        (__attribute__((address_space(3))) unsigned*)l, 16, 0, 0);
}

// ---------------- sort prep ----------------

__global__ __launch_bounds__(256) void hist_block(const int* __restrict__ pol,
                                                  int* __restrict__ blockhist,
                                                  int* __restrict__ rowidx) {
    __shared__ int lc[P_SZ];
    int t = threadIdx.x;
    if (t < P_SZ) lc[t] = 0;
    __syncthreads();
    int gid = blockIdx.x * 256 + t;
    rowidx[gid] = -1;
    if (gid < BPAD - B_SZ) rowidx[B_SZ + gid] = -1;
    atomicAdd(&lc[pol[gid]], 1);
    __syncthreads();
    if (t < P_SZ) blockhist[blockIdx.x * P_SZ + t] = lc[t];
}

__global__ __launch_bounds__(64) void prefix_kernel(const int* __restrict__ blockhist,
                                                    int* __restrict__ counts,
                                                    int* __restrict__ cursors,
                                                    int* __restrict__ blk_p) {
    int t = threadIdx.x;
    if (t < P_SZ) {
        int s = 0;
        for (int b = 0; b < NSEG; ++b) s += blockhist[b * P_SZ + t];
        counts[t] = s;
    }
    __syncthreads();
    if (t == 0) {
        int run = 0;   // 256-aligned running offset
        for (int p = 0; p < P_SZ; ++p) {
            cursors[p] = run;
            int nb = (counts[p] + 255) >> 8;
            for (int b = 0; b < nb; ++b) blk_p[(run >> 8) + b] = p;
            run += nb * 256;
        }
        for (int b = run >> 8; b < MB_MAX; ++b) blk_p[b] = -1;
    }
}

__global__ __launch_bounds__(256) void scatter_agg(const int* __restrict__ pol,
                                                   int* __restrict__ cursors,
                                                   int* __restrict__ rowidx) {
    __shared__ int lc[P_SZ], base_s[P_SZ];
    int t = threadIdx.x;
    if (t < P_SZ) lc[t] = 0;
    __syncthreads();
    int i = blockIdx.x * 256 + t;
    int p = pol[i];
    int lpos = atomicAdd(&lc[p], 1);
    __syncthreads();
    if (t < P_SZ) base_s[t] = atomicAdd(&cursors[t], lc[t]);
    __syncthreads();
    rowidx[base_s[p] + lpos] = i;
}

// ---------------- prep_all: fused x-gather/convert + weight transposes ----------------

__global__ __launch_bounds__(256) void prep_all(const float* __restrict__ latents,
                                                const float* __restrict__ actions,
                                                const int* __restrict__ rowidx,
                                                const float* __restrict__ W1,
                                                const float* __restrict__ W2,
                                                bf16_t* __restrict__ xs,
                                                bf16_t* __restrict__ w1t,
                                                bf16_t* __restrict__ w2t) {
    int bx = blockIdx.x;
    int tid = threadIdx.x;
    if (bx < PREP_BLOCKS) {
        int idx = bx * 256 + tid;
        int s = idx / 72;
        int col = (idx - s * 72) * 8;
        int g = rowidx[s];
        bf16x8 o;
        if (g < 0) {
            o = (bf16x8){0,0,0,0,0,0,0,0};
        } else {
            const float* src;
            if (col < D_SZ) src = latents + (size_t)g * D_SZ + col;
            else            src = actions + (size_t)g * A_SZ + (col - D_SZ);
            f32x4 v0 = *(const f32x4*)src;
            f32x4 v1 = *(const f32x4*)(src + 4);
            o[0] = (bf16_t)v0[0]; o[1] = (bf16_t)v0[1]; o[2] = (bf16_t)v0[2]; o[3] = (bf16_t)v0[3];
            o[4] = (bf16_t)v1[0]; o[5] = (bf16_t)v1[1]; o[6] = (bf16_t)v1[2]; o[7] = (bf16_t)v1[3];
        }
        *(bf16x8*)(xs + (size_t)s * K1 + col) = o;
        return;
    }
    int tz = bx - PREP_BLOCKS;        // 0..16383
    int z = tz >> 10;                 // 0..15
    int rem = tz & 1023;
    int k0 = (rem & 31) * 32, n0 = (rem >> 5) * 32;
    int K = (z < P_SZ) ? K1 : H_SZ;
    int N = (z < P_SZ) ? H_SZ : D_SZ;
    if (k0 >= K || n0 >= N) return;
    int p = z & 7;
    const float* Wp = ((z < P_SZ) ? W1 : W2) + (size_t)p * K * N;
    bf16_t* WTp = ((z < P_SZ) ? w1t : w2t) + (size_t)p * N * K;
    __shared__ float ls[32][33];
    {   // vectorized tile load: one f32x4 per thread covers the 32x32 tile
        int kk = tid >> 3, nn = (tid & 7) * 4;
        f32x4 v = *(const f32x4*)&Wp[(size_t)(k0 + kk) * N + n0 + nn];
        ls[kk][nn]     = v[0];
        ls[kk][nn + 1] = v[1];
        ls[kk][nn + 2] = v[2];
        ls[kk][nn + 3] = v[3];
    }
    __syncthreads();
#pragma unroll
    for (int e = 0; e < 2; ++e) {
        int idx = e * 256 + tid;
        int nn = idx >> 4, kp = (idx & 15) * 2;
        union { bf16_t h[2]; unsigned u; } pk;
        pk.h[0] = (bf16_t)ls[kp][nn];
        pk.h[1] = (bf16_t)ls[kp + 1][nn];
        *(unsigned*)&WTp[(size_t)(n0 + nn) * K + k0 + kp] = pk.u;
    }
}

// ---------------- GEMMs: BM=128, 4 waves in 2x2 wave grid, m97 2-barrier loop -------
// Round-2 post-mortem: counted-vmcnt / explicit dbuf both LOST to the plain 2-barrier
// loop (compiler orders glds-vs-ds_read conservatively; m99/m100: explicit pipelining
// is null when occupancy is adequate). The actual deficit was blocks/CU: 576 blocks =
// 2.25/CU. Fix: 128-row tiles -> 1152 blocks, smaller acc -> 3-4 blocks/CU resident,
// the m97 regime (12-16 waves/CU) where intra-CU overlap hides the barrier drain.
// XOR chunk swizzle unchanged (0 conflicts measured). Policy segments are 256-aligned
// so p = blk_p[blockIdx.x>>1] is uniform per 128-row block.

__global__ __launch_bounds__(256, 3) void gemm1_kernel(
    const bf16_t* __restrict__ xs, const bf16_t* __restrict__ w1t,
    const float* __restrict__ b1, const int* __restrict__ blk_p,
    bf16_t* __restrict__ h) {

    const int p = blk_p[blockIdx.x >> 1];
    if (p < 0) return;
    const int m0 = blockIdx.x * 128;
    const int n0 = blockIdx.y * 128;

    __shared__ __align__(16) bf16_t As[128 * 32];   // 8 KB
    __shared__ __align__(16) bf16_t Bs[128 * 32];   // 8 KB

    const int tid = threadIdx.x;
    const int wave = tid >> 6, lane = tid & 63;

    // A: 512 16B-chunks, 8 slots of 64; wave handles slots wave*2+i
    const bf16_t* a_src[2]; bf16_t* a_dst[2];
#pragma unroll
    for (int i = 0; i < 2; ++i) {
        int c = (wave * 2 + i) * 64 + lane;
        int r = c >> 2;
        int kl = (c & 3) ^ ((r >> 1) & 3);
        a_src[i] = xs + (size_t)(m0 + r) * K1 + kl * 8;
        a_dst[i] = As + c * 8;
    }
    // B: 512 chunks, 8 slots; wave handles slots wave*2+i
    const bf16_t* b_src[2]; bf16_t* b_dst[2];
#pragma unroll
    for (int i = 0; i < 2; ++i) {
        int c = (wave * 2 + i) * 64 + lane;
        int r = c >> 2;
        int kl = (c & 3) ^ ((r >> 1) & 3);
        b_src[i] = w1t + ((size_t)p * H_SZ + n0 + r) * K1 + kl * 8;
        b_dst[i] = Bs + c * 8;
    }

    const int l16 = lane & 15, qd = lane >> 4;
    const int swz = (l16 >> 1) & 3;
    const int wr = wave >> 1, wc = wave & 1;   // 2x2 wave grid; wave tile 64x64
    int aoff[4], boff[4];
#pragma unroll
    for (int i = 0; i < 4; ++i) aoff[i] = (wr * 64 + i * 16 + l16) * 32 + ((qd ^ swz) * 8);
#pragma unroll
    for (int j = 0; j < 4; ++j) boff[j] = (wc * 64 + j * 16 + l16) * 32 + ((qd ^ swz) * 8);

    f32x4 acc[4][4];
#pragma unroll
    for (int i = 0; i < 4; ++i)
#pragma unroll
        for (int j = 0; j < 4; ++j)
            acc[i][j] = (f32x4){0.f, 0.f, 0.f, 0.f};

    for (int kt = 0; kt < K1; kt += 32) {
        __syncthreads();   // previous iter's frags consumed
#pragma unroll
        for (int i = 0; i < 2; ++i) glds16(a_src[i] + kt, a_dst[i]);
#pragma unroll
        for (int i = 0; i < 2; ++i) glds16(b_src[i] + kt, b_dst[i]);
        __syncthreads();   // staging complete (compiler inserts vmcnt(0))
        bf16x8 af[4], bfv[4];
#pragma unroll
        for (int i = 0; i < 4; ++i) af[i] = *(const bf16x8*)(As + aoff[i]);
#pragma unroll
        for (int j = 0; j < 4; ++j) bfv[j] = *(const bf16x8*)(Bs + boff[j]);
#pragma unroll
        for (int i = 0; i < 4; ++i)
#pragma unroll
            for (int j = 0; j < 4; ++j)
                acc[i][j] = __builtin_amdgcn_mfma_f32_16x16x32_bf16(af[i], bfv[j], acc[i][j], 0, 0, 0);
    }

    // epilogue: bias + relu -> h (padded sorted layout)
#pragma unroll
    for (int i = 0; i < 4; ++i) {
#pragma unroll
        for (int r = 0; r < 4; ++r) {
            int ml = wr * 64 + i * 16 + qd * 4 + r;     // C/D: row = quad*4 + reg
            size_t row = (size_t)(m0 + ml);
#pragma unroll
            for (int j = 0; j < 4; ++j) {
                int n = n0 + wc * 64 + j * 16 + l16;    // C/D: col = lane&15
                float v = acc[i][j][r] + b1[p * H_SZ + n];
                h[row * H_SZ + n] = (bf16_t)fmaxf(v, 0.f);
            }
        }
    }
}

__global__ __launch_bounds__(256, 4) void gemm2_kernel(
    const bf16_t* __restrict__ h, const bf16_t* __restrict__ w2t,
    const float* __restrict__ b2, const int* __restrict__ blk_p,
    const int* __restrict__ rowidx, float* __restrict__ out) {

    const int p = blk_p[blockIdx.x >> 1];
    if (p < 0) return;
    const int m0 = blockIdx.x * 128;
    const int n0 = blockIdx.y * 64;

    __shared__ __align__(16) bf16_t As[128 * 32];   // 8 KB
    __shared__ __align__(16) bf16_t Bs[64 * 32];    // 4 KB

    const int tid = threadIdx.x;
    const int wave = tid >> 6, lane = tid & 63;

    // A: 512 chunks, 8 slots; wave handles slots wave*2+i
    const bf16_t* a_src[2]; bf16_t* a_dst[2];
#pragma unroll
    for (int i = 0; i < 2; ++i) {
        int c = (wave * 2 + i) * 64 + lane;
        int r = c >> 2;
        int kl = (c & 3) ^ ((r >> 1) & 3);
        a_src[i] = h + (size_t)(m0 + r) * H_SZ + kl * 8;
        a_dst[i] = As + c * 8;
    }
    // B: 256 chunks, 4 slots; wave handles slot `wave`
    const bf16_t* b_src0; bf16_t* b_dst0;
    {
        int c = wave * 64 + lane;
        int r = c >> 2;
        int kl = (c & 3) ^ ((r >> 1) & 3);
        b_src0 = w2t + ((size_t)p * D_SZ + n0 + r) * H_SZ + kl * 8;
        b_dst0 = Bs + c * 8;
    }

    const int l16 = lane & 15, qd = lane >> 4;
    const int swz = (l16 >> 1) & 3;
    const int wr = wave >> 1, wc = wave & 1;   // 2x2 wave grid; wave tile 64x32
    int aoff[4], boff[2];
#pragma unroll
    for (int i = 0; i < 4; ++i) aoff[i] = (wr * 64 + i * 16 + l16) * 32 + ((qd ^ swz) * 8);
#pragma unroll
    for (int j = 0; j < 2; ++j) boff[j] = (wc * 32 + j * 16 + l16) * 32 + ((qd ^ swz) * 8);

    f32x4 acc[4][2];
#pragma unroll
    for (int i = 0; i < 4; ++i)
#pragma unroll
        for (int j = 0; j < 2; ++j)
            acc[i][j] = (f32x4){0.f, 0.f, 0.f, 0.f};

    for (int kt = 0; kt < H_SZ; kt += 32) {
        __syncthreads();
#pragma unroll
        for (int i = 0; i < 2; ++i) glds16(a_src[i] + kt, a_dst[i]);
        glds16(b_src0 + kt, b_dst0);
        __syncthreads();
        bf16x8 af[4], bfv[2];
#pragma unroll
        for (int i = 0; i < 4; ++i) af[i] = *(const bf16x8*)(As + aoff[i]);
#pragma unroll
        for (int j = 0; j < 2; ++j) bfv[j] = *(const bf16x8*)(Bs + boff[j]);
#pragma unroll
        for (int i = 0; i < 4; ++i)
#pragma unroll
            for (int j = 0; j < 2; ++j)
                acc[i][j] = __builtin_amdgcn_mfma_f32_16x16x32_bf16(af[i], bfv[j], acc[i][j], 0, 0, 0);
    }

    // epilogue: bias, scatter to original rows; pad rows masked
#pragma unroll
    for (int i = 0; i < 4; ++i) {
#pragma unroll
        for (int r = 0; r < 4; ++r) {
            int ml = wr * 64 + i * 16 + qd * 4 + r;
            int g = rowidx[m0 + ml];
            if (g >= 0) {
                size_t orow = (size_t)g * D_SZ;
#pragma unroll
                for (int j = 0; j < 2; ++j) {
                    int n = n0 + wc * 32 + j * 16 + l16;
                    out[orow + n] = acc[i][j][r] + b2[p * D_SZ + n];
                }
            }
        }
    }
}

// ---------------- launch ----------------

extern "C" void kernel_launch(void* const* d_in, const int* in_sizes, int n_in,
                              void* d_out, int out_size, void* d_ws, size_t ws_size,
                              hipStream_t stream) {
    const float* latents = (const float*)d_in[0];
    const float* actions = (const float*)d_in[1];
    const int*   pol     = (const int*)d_in[2];
    const float* W1      = (const float*)d_in[3];
    const float* b1      = (const float*)d_in[4];
    const float* W2      = (const float*)d_in[5];
    const float* b2      = (const float*)d_in[6];
    float* out = (float*)d_out;

    char* ws = (char*)d_ws;
    int* counts    = (int*)ws;
    int* cursors   = counts + P_SZ;
    int* blk_p     = cursors + P_SZ;
    int* blockhist = blk_p + MB_MAX;
    int* rowidx    = blockhist + NSEG * P_SZ;
    size_t pos = ((size_t)(2 * P_SZ + MB_MAX + NSEG * P_SZ + BPAD) * sizeof(int) + 255) & ~(size_t)255;
    bf16_t* xs  = (bf16_t*)(ws + pos);  pos += (size_t)BPAD * K1 * 2;
    bf16_t* hbuf= (bf16_t*)(ws + pos);  pos += (size_t)BPAD * H_SZ * 2;
    bf16_t* w1t = (bf16_t*)(ws + pos);  pos += (size_t)P_SZ * H_SZ * K1 * 2;
    bf16_t* w2t = (bf16_t*)(ws + pos);  pos += (size_t)P_SZ * D_SZ * H_SZ * 2;

    hist_block<<<NSEG, 256, 0, stream>>>(pol, blockhist, rowidx);
    prefix_kernel<<<1, 64, 0, stream>>>(blockhist, counts, cursors, blk_p);
    scatter_agg<<<NSEG, 256, 0, stream>>>(pol, cursors, rowidx);
    prep_all<<<PREP_BLOCKS + TRANS_BLOCKS, 256, 0, stream>>>(
        latents, actions, rowidx, W1, W2, xs, w1t, w2t);
    gemm1_kernel<<<dim3(BPAD / 128, H_SZ / 128), 256, 0, stream>>>(xs, w1t, b1, blk_p, hbuf);
    gemm2_kernel<<<dim3(BPAD / 128, D_SZ / 64), 256, 0, stream>>>(hbuf, w2t, b2, blk_p, rowidx, out);
}

// Round 4
// 201.087 us; speedup vs baseline: 1.1963x; 1.0412x over previous
//
#include <hip/hip_runtime.h>
#include <hip/hip_bf16.h>
#include <stdint.h>

#define B_SZ 16384
#define P_SZ 8
#define D_SZ 512
#define A_SZ 64
#define K1 576    // D + A
#define H_SZ 1024
#define NSEG 64
#define MB_MAX 72               // max 256-row m-blocks after per-policy padding
#define BPAD (B_SZ + P_SZ*256)  // 18432 padded sorted-row capacity
#define PREP_BLOCKS (BPAD * 72 / 256)   // 5184
#define TRANS_BLOCKS (32 * 32 * 16)     // 16384
#define G1_GRID (BPAD / 128 * (H_SZ / 128))   // 1152
#define G2_GRID (BPAD / 128 * (D_SZ / 64))    // 1152

typedef __bf16 bf16_t;
typedef __bf16 bf16x8 __attribute__((ext_vector_type(8)));
typedef float f32x4 __attribute__((ext_vector_type(4)));

__device__ __forceinline__ void glds16(const void* g, void* l) {
    __builtin_amdgcn_global_load_lds(
        (const __attribute__((address_space(1))) unsigned*)g,
        (__attribute__((address_space(3))) unsigned*)l, 16, 0, 0);
}

// ---------------- sort prep ----------------

__global__ __launch_bounds__(256) void hist_block(const int* __restrict__ pol,
                                                  int* __restrict__ blockhist,
                                                  int* __restrict__ rowidx) {
    __shared__ int lc[P_SZ];
    int t = threadIdx.x;
    if (t < P_SZ) lc[t] = 0;
    __syncthreads();
    int gid = blockIdx.x * 256 + t;
    rowidx[gid] = -1;
    if (gid < BPAD - B_SZ) rowidx[B_SZ + gid] = -1;
    atomicAdd(&lc[pol[gid]], 1);
    __syncthreads();
    if (t < P_SZ) blockhist[blockIdx.x * P_SZ + t] = lc[t];
}

__global__ __launch_bounds__(64) void prefix_kernel(const int* __restrict__ blockhist,
                                                    int* __restrict__ counts,
                                                    int* __restrict__ cursors,
                                                    int* __restrict__ blk_p) {
    int t = threadIdx.x;
    if (t < P_SZ) {
        int s = 0;
        for (int b = 0; b < NSEG; ++b) s += blockhist[b * P_SZ + t];
        counts[t] = s;
    }
    __syncthreads();
    if (t == 0) {
        int run = 0;   // 256-aligned running offset
        for (int p = 0; p < P_SZ; ++p) {
            cursors[p] = run;
            int nb = (counts[p] + 255) >> 8;
            for (int b = 0; b < nb; ++b) blk_p[(run >> 8) + b] = p;
            run += nb * 256;
        }
        for (int b = run >> 8; b < MB_MAX; ++b) blk_p[b] = -1;
    }
}

__global__ __launch_bounds__(256) void scatter_agg(const int* __restrict__ pol,
                                                   int* __restrict__ cursors,
                                                   int* __restrict__ rowidx) {
    __shared__ int lc[P_SZ], base_s[P_SZ];
    int t = threadIdx.x;
    if (t < P_SZ) lc[t] = 0;
    __syncthreads();
    int i = blockIdx.x * 256 + t;
    int p = pol[i];
    int lpos = atomicAdd(&lc[p], 1);
    __syncthreads();
    if (t < P_SZ) base_s[t] = atomicAdd(&cursors[t], lc[t]);
    __syncthreads();
    rowidx[base_s[p] + lpos] = i;
}

// ---------------- prep_all: fused x-gather/convert + weight transposes ----------------

__global__ __launch_bounds__(256) void prep_all(const float* __restrict__ latents,
                                                const float* __restrict__ actions,
                                                const int* __restrict__ rowidx,
                                                const float* __restrict__ W1,
                                                const float* __restrict__ W2,
                                                bf16_t* __restrict__ xs,
                                                bf16_t* __restrict__ w1t,
                                                bf16_t* __restrict__ w2t) {
    int bx = blockIdx.x;
    int tid = threadIdx.x;
    if (bx < PREP_BLOCKS) {
        int idx = bx * 256 + tid;
        int s = idx / 72;
        int col = (idx - s * 72) * 8;
        int g = rowidx[s];
        bf16x8 o;
        if (g < 0) {
            o = (bf16x8){0,0,0,0,0,0,0,0};
        } else {
            const float* src;
            if (col < D_SZ) src = latents + (size_t)g * D_SZ + col;
            else            src = actions + (size_t)g * A_SZ + (col - D_SZ);
            f32x4 v0 = *(const f32x4*)src;
            f32x4 v1 = *(const f32x4*)(src + 4);
            o[0] = (bf16_t)v0[0]; o[1] = (bf16_t)v0[1]; o[2] = (bf16_t)v0[2]; o[3] = (bf16_t)v0[3];
            o[4] = (bf16_t)v1[0]; o[5] = (bf16_t)v1[1]; o[6] = (bf16_t)v1[2]; o[7] = (bf16_t)v1[3];
        }
        *(bf16x8*)(xs + (size_t)s * K1 + col) = o;
        return;
    }
    int tz = bx - PREP_BLOCKS;        // 0..16383
    int z = tz >> 10;                 // 0..15
    int rem = tz & 1023;
    int k0 = (rem & 31) * 32, n0 = (rem >> 5) * 32;
    int K = (z < P_SZ) ? K1 : H_SZ;
    int N = (z < P_SZ) ? H_SZ : D_SZ;
    if (k0 >= K || n0 >= N) return;
    int p = z & 7;
    const float* Wp = ((z < P_SZ) ? W1 : W2) + (size_t)p * K * N;
    bf16_t* WTp = ((z < P_SZ) ? w1t : w2t) + (size_t)p * N * K;
    __shared__ float ls[32][33];
    {   // vectorized tile load: one f32x4 per thread covers the 32x32 tile
        int kk = tid >> 3, nn = (tid & 7) * 4;
        f32x4 v = *(const f32x4*)&Wp[(size_t)(k0 + kk) * N + n0 + nn];
        ls[kk][nn]     = v[0];
        ls[kk][nn + 1] = v[1];
        ls[kk][nn + 2] = v[2];
        ls[kk][nn + 3] = v[3];
    }
    __syncthreads();
#pragma unroll
    for (int e = 0; e < 2; ++e) {
        int idx = e * 256 + tid;
        int nn = idx >> 4, kp = (idx & 15) * 2;
        union { bf16_t h[2]; unsigned u; } pk;
        pk.h[0] = (bf16_t)ls[kp][nn];
        pk.h[1] = (bf16_t)ls[kp + 1][nn];
        *(unsigned*)&WTp[(size_t)(n0 + nn) * K + k0 + kp] = pk.u;
    }
}

// ---------------- GEMMs: BM=128, 2x2 wave grid, m97 2-barrier loop, XCD-local n-sweep
// Round-3 post-mortem: occupancy 11->33% with NO speedup -> serializer is off-CU.
// Grid (m,n) with m-fastest linearization spread the 8 n-blocks sharing one A-tile
// across all 8 XCDs: every A-tile (xs/h) was re-pulled through L3 into 8 different
// L2s (~8x cross-die traffic). Fix (T1): 1D grid, wid=(b&7)*144+(b>>3) gives each
// XCD 18 consecutive m-blocks with n fastest -> A-tile (256KB) + B panel (~1MB)
// stay L2-resident per XCD. Bijective (1152%8==0). Everything else identical to the
// passing round-3 kernel (0 bank conflicts, no spills).

__global__ __launch_bounds__(256, 3) void gemm1_kernel(
    const bf16_t* __restrict__ xs, const bf16_t* __restrict__ w1t,
    const float* __restrict__ b1, const int* __restrict__ blk_p,
    bf16_t* __restrict__ h) {

    const int b = blockIdx.x;
    const int wid = (b & 7) * (G1_GRID / 8) + (b >> 3);   // XCD-contiguous work id
    const int mb = wid >> 3;          // 0..143  (n fastest within an XCD)
    const int nb = wid & 7;           // 0..7
    const int p = blk_p[mb >> 1];
    if (p < 0) return;
    const int m0 = mb * 128;
    const int n0 = nb * 128;

    __shared__ __align__(16) bf16_t As[128 * 32];   // 8 KB
    __shared__ __align__(16) bf16_t Bs[128 * 32];   // 8 KB

    const int tid = threadIdx.x;
    const int wave = tid >> 6, lane = tid & 63;

    // A: 512 16B-chunks, 8 slots of 64; wave handles slots wave*2+i
    const bf16_t* a_src[2]; bf16_t* a_dst[2];
#pragma unroll
    for (int i = 0; i < 2; ++i) {
        int c = (wave * 2 + i) * 64 + lane;
        int r = c >> 2;
        int kl = (c & 3) ^ ((r >> 1) & 3);
        a_src[i] = xs + (size_t)(m0 + r) * K1 + kl * 8;
        a_dst[i] = As + c * 8;
    }
    // B: 512 chunks, 8 slots; wave handles slots wave*2+i
    const bf16_t* b_src[2]; bf16_t* b_dst[2];
#pragma unroll
    for (int i = 0; i < 2; ++i) {
        int c = (wave * 2 + i) * 64 + lane;
        int r = c >> 2;
        int kl = (c & 3) ^ ((r >> 1) & 3);
        b_src[i] = w1t + ((size_t)p * H_SZ + n0 + r) * K1 + kl * 8;
        b_dst[i] = Bs + c * 8;
    }

    const int l16 = lane & 15, qd = lane >> 4;
    const int swz = (l16 >> 1) & 3;
    const int wr = wave >> 1, wc = wave & 1;   // 2x2 wave grid; wave tile 64x64
    int aoff[4], boff[4];
#pragma unroll
    for (int i = 0; i < 4; ++i) aoff[i] = (wr * 64 + i * 16 + l16) * 32 + ((qd ^ swz) * 8);
#pragma unroll
    for (int j = 0; j < 4; ++j) boff[j] = (wc * 64 + j * 16 + l16) * 32 + ((qd ^ swz) * 8);

    f32x4 acc[4][4];
#pragma unroll
    for (int i = 0; i < 4; ++i)
#pragma unroll
        for (int j = 0; j < 4; ++j)
            acc[i][j] = (f32x4){0.f, 0.f, 0.f, 0.f};

    for (int kt = 0; kt < K1; kt += 32) {
        __syncthreads();   // previous iter's frags consumed
#pragma unroll
        for (int i = 0; i < 2; ++i) glds16(a_src[i] + kt, a_dst[i]);
#pragma unroll
        for (int i = 0; i < 2; ++i) glds16(b_src[i] + kt, b_dst[i]);
        __syncthreads();   // staging complete (compiler inserts vmcnt(0))
        bf16x8 af[4], bfv[4];
#pragma unroll
        for (int i = 0; i < 4; ++i) af[i] = *(const bf16x8*)(As + aoff[i]);
#pragma unroll
        for (int j = 0; j < 4; ++j) bfv[j] = *(const bf16x8*)(Bs + boff[j]);
#pragma unroll
        for (int i = 0; i < 4; ++i)
#pragma unroll
            for (int j = 0; j < 4; ++j)
                acc[i][j] = __builtin_amdgcn_mfma_f32_16x16x32_bf16(af[i], bfv[j], acc[i][j], 0, 0, 0);
    }

    // epilogue: bias + relu -> h (padded sorted layout)
#pragma unroll
    for (int i = 0; i < 4; ++i) {
#pragma unroll
        for (int r = 0; r < 4; ++r) {
            int ml = wr * 64 + i * 16 + qd * 4 + r;     // C/D: row = quad*4 + reg
            size_t row = (size_t)(m0 + ml);
#pragma unroll
            for (int j = 0; j < 4; ++j) {
                int n = n0 + wc * 64 + j * 16 + l16;    // C/D: col = lane&15
                float v = acc[i][j][r] + b1[p * H_SZ + n];
                h[row * H_SZ + n] = (bf16_t)fmaxf(v, 0.f);
            }
        }
    }
}

__global__ __launch_bounds__(256, 4) void gemm2_kernel(
    const bf16_t* __restrict__ h, const bf16_t* __restrict__ w2t,
    const float* __restrict__ b2, const int* __restrict__ blk_p,
    const int* __restrict__ rowidx, float* __restrict__ out) {

    const int b = blockIdx.x;
    const int wid = (b & 7) * (G2_GRID / 8) + (b >> 3);   // XCD-contiguous work id
    const int mb = wid >> 3;          // 0..143  (n fastest within an XCD)
    const int nb = wid & 7;           // 0..7
    const int p = blk_p[mb >> 1];
    if (p < 0) return;
    const int m0 = mb * 128;
    const int n0 = nb * 64;

    __shared__ __align__(16) bf16_t As[128 * 32];   // 8 KB
    __shared__ __align__(16) bf16_t Bs[64 * 32];    // 4 KB

    const int tid = threadIdx.x;
    const int wave = tid >> 6, lane = tid & 63;

    // A: 512 chunks, 8 slots; wave handles slots wave*2+i
    const bf16_t* a_src[2]; bf16_t* a_dst[2];
#pragma unroll
    for (int i = 0; i < 2; ++i) {
        int c = (wave * 2 + i) * 64 + lane;
        int r = c >> 2;
        int kl = (c & 3) ^ ((r >> 1) & 3);
        a_src[i] = h + (size_t)(m0 + r) * H_SZ + kl * 8;
        a_dst[i] = As + c * 8;
    }
    // B: 256 chunks, 4 slots; wave handles slot `wave`
    const bf16_t* b_src0; bf16_t* b_dst0;
    {
        int c = wave * 64 + lane;
        int r = c >> 2;
        int kl = (c & 3) ^ ((r >> 1) & 3);
        b_src0 = w2t + ((size_t)p * D_SZ + n0 + r) * H_SZ + kl * 8;
        b_dst0 = Bs + c * 8;
    }

    const int l16 = lane & 15, qd = lane >> 4;
    const int swz = (l16 >> 1) & 3;
    const int wr = wave >> 1, wc = wave & 1;   // 2x2 wave grid; wave tile 64x32
    int aoff[4], boff[2];
#pragma unroll
    for (int i = 0; i < 4; ++i) aoff[i] = (wr * 64 + i * 16 + l16) * 32 + ((qd ^ swz) * 8);
#pragma unroll
    for (int j = 0; j < 2; ++j) boff[j] = (wc * 32 + j * 16 + l16) * 32 + ((qd ^ swz) * 8);

    f32x4 acc[4][2];
#pragma unroll
    for (int i = 0; i < 4; ++i)
#pragma unroll
        for (int j = 0; j < 2; ++j)
            acc[i][j] = (f32x4){0.f, 0.f, 0.f, 0.f};

    for (int kt = 0; kt < H_SZ; kt += 32) {
        __syncthreads();
#pragma unroll
        for (int i = 0; i < 2; ++i) glds16(a_src[i] + kt, a_dst[i]);
        glds16(b_src0 + kt, b_dst0);
        __syncthreads();
        bf16x8 af[4], bfv[2];
#pragma unroll
        for (int i = 0; i < 4; ++i) af[i] = *(const bf16x8*)(As + aoff[i]);
#pragma unroll
        for (int j = 0; j < 2; ++j) bfv[j] = *(const bf16x8*)(Bs + boff[j]);
#pragma unroll
        for (int i = 0; i < 4; ++i)
#pragma unroll
            for (int j = 0; j < 2; ++j)
                acc[i][j] = __builtin_amdgcn_mfma_f32_16x16x32_bf16(af[i], bfv[j], acc[i][j], 0, 0, 0);
    }

    // epilogue: bias, scatter to original rows; pad rows masked
#pragma unroll
    for (int i = 0; i < 4; ++i) {
#pragma unroll
        for (int r = 0; r < 4; ++r) {
            int ml = wr * 64 + i * 16 + qd * 4 + r;
            int g = rowidx[m0 + ml];
            if (g >= 0) {
                size_t orow = (size_t)g * D_SZ;
#pragma unroll
                for (int j = 0; j < 2; ++j) {
                    int n = n0 + wc * 32 + j * 16 + l16;
                    out[orow + n] = acc[i][j][r] + b2[p * D_SZ + n];
                }
            }
        }
    }
}

// ---------------- launch ----------------

extern "C" void kernel_launch(void* const* d_in, const int* in_sizes, int n_in,
                              void* d_out, int out_size, void* d_ws, size_t ws_size,
                              hipStream_t stream) {
    const float* latents = (const float*)d_in[0];
    const float* actions = (const float*)d_in[1];
    const int*   pol     = (const int*)d_in[2];
    const float* W1      = (const float*)d_in[3];
    const float* b1      = (const float*)d_in[4];
    const float* W2      = (const float*)d_in[5];
    const float* b2      = (const float*)d_in[6];
    float* out = (float*)d_out;

    char* ws = (char*)d_ws;
    int* counts    = (int*)ws;
    int* cursors   = counts + P_SZ;
    int* blk_p     = cursors + P_SZ;
    int* blockhist = blk_p + MB_MAX;
    int* rowidx    = blockhist + NSEG * P_SZ;
    size_t pos = ((size_t)(2 * P_SZ + MB_MAX + NSEG * P_SZ + BPAD) * sizeof(int) + 255) & ~(size_t)255;
    bf16_t* xs  = (bf16_t*)(ws + pos);  pos += (size_t)BPAD * K1 * 2;
    bf16_t* hbuf= (bf16_t*)(ws + pos);  pos += (size_t)BPAD * H_SZ * 2;
    bf16_t* w1t = (bf16_t*)(ws + pos);  pos += (size_t)P_SZ * H_SZ * K1 * 2;
    bf16_t* w2t = (bf16_t*)(ws + pos);  pos += (size_t)P_SZ * D_SZ * H_SZ * 2;

    hist_block<<<NSEG, 256, 0, stream>>>(pol, blockhist, rowidx);
    prefix_kernel<<<1, 64, 0, stream>>>(blockhist, counts, cursors, blk_p);
    scatter_agg<<<NSEG, 256, 0, stream>>>(pol, cursors, rowidx);
    prep_all<<<PREP_BLOCKS + TRANS_BLOCKS, 256, 0, stream>>>(
        latents, actions, rowidx, W1, W2, xs, w1t, w2t);
    gemm1_kernel<<<G1_GRID, 256, 0, stream>>>(xs, w1t, b1, blk_p, hbuf);
    gemm2_kernel<<<G2_GRID, 256, 0, stream>>>(hbuf, w2t, b2, blk_p, rowidx, out);
}

// Round 5
// 192.588 us; speedup vs baseline: 1.2491x; 1.0441x over previous
//
#include <hip/hip_runtime.h>
#include <hip/hip_bf16.h>
#include <stdint.h>

#define B_SZ 16384
#define P_SZ 8
#define D_SZ 512
#define A_SZ 64
#define K1 576    // D + A
#define H_SZ 1024
#define NSEG 64
#define MB_MAX 72               // max 256-row m-blocks after per-policy padding
#define BPAD (B_SZ + P_SZ*256)  // 18432 padded sorted-row capacity
#define PREP_BLOCKS (BPAD * 72 / 256)   // 5184
#define TR1_BLOCKS (P_SZ * 9 * 16)      // 1152  (576/64 x 1024/64)
#define TR2_BLOCKS (P_SZ * 16 * 8)      // 1024  (1024/64 x 512/64)
#define G1_GRID (BPAD / 128 * (H_SZ / 128))   // 1152
#define G2_GRID (BPAD / 128 * (D_SZ / 64))    // 1152

typedef __bf16 bf16_t;
typedef __bf16 bf16x8 __attribute__((ext_vector_type(8)));
typedef float f32x4 __attribute__((ext_vector_type(4)));

__device__ __forceinline__ void glds16(const void* g, void* l) {
    __builtin_amdgcn_global_load_lds(
        (const __attribute__((address_space(1))) unsigned*)g,
        (__attribute__((address_space(3))) unsigned*)l, 16, 0, 0);
}

// ---------------- sort prep ----------------

__global__ __launch_bounds__(256) void hist_block(const int* __restrict__ pol,
                                                  int* __restrict__ blockhist,
                                                  int* __restrict__ rowidx) {
    __shared__ int lc[P_SZ];
    int t = threadIdx.x;
    if (t < P_SZ) lc[t] = 0;
    __syncthreads();
    int gid = blockIdx.x * 256 + t;
    rowidx[gid] = -1;
    if (gid < BPAD - B_SZ) rowidx[B_SZ + gid] = -1;
    atomicAdd(&lc[pol[gid]], 1);
    __syncthreads();
    if (t < P_SZ) blockhist[blockIdx.x * P_SZ + t] = lc[t];
}

// parallel reduction (was: 64 serial dependent global reads on one thread)
__global__ __launch_bounds__(256) void prefix_kernel(const int* __restrict__ blockhist,
                                                     int* __restrict__ counts,
                                                     int* __restrict__ cursors,
                                                     int* __restrict__ blk_p) {
    __shared__ int csh[P_SZ];
    int t = threadIdx.x;
    int p = t >> 5, i = t & 31;          // 8 policies x 32 lanes
    int s = blockhist[i * P_SZ + p] + blockhist[(i + 32) * P_SZ + p];
#pragma unroll
    for (int m = 16; m >= 1; m >>= 1) s += __shfl_xor(s, m, 32);
    if (i == 0) csh[p] = s;
    __syncthreads();
    if (t == 0) {
        int run = 0;
        for (int pp = 0; pp < P_SZ; ++pp) {
            counts[pp] = csh[pp];
            cursors[pp] = run;
            run += ((csh[pp] + 255) >> 8) * 256;
        }
    }
    if (t < MB_MAX) {
        int run = 0, val = -1;
#pragma unroll
        for (int pp = 0; pp < P_SZ; ++pp) {
            int nb = (csh[pp] + 255) >> 8;
            if (t >= run && t < run + nb) val = pp;
            run += nb;
        }
        blk_p[t] = val;
    }
}

__global__ __launch_bounds__(256) void scatter_agg(const int* __restrict__ pol,
                                                   int* __restrict__ cursors,
                                                   int* __restrict__ rowidx) {
    __shared__ int lc[P_SZ], base_s[P_SZ];
    int t = threadIdx.x;
    if (t < P_SZ) lc[t] = 0;
    __syncthreads();
    int i = blockIdx.x * 256 + t;
    int p = pol[i];
    int lpos = atomicAdd(&lc[p], 1);
    __syncthreads();
    if (t < P_SZ) base_s[t] = atomicAdd(&cursors[t], lc[t]);
    __syncthreads();
    rowidx[base_s[p] + lpos] = i;
}

// ---------------- prep_all: fused x-gather/convert + weight transposes ----------------
// Transpose path reworked: exact grid (no dead blocks), 64x64 f32 tiles, packed
// bf16x8 stores (8 consecutive threads write one full 128B output row).

__global__ __launch_bounds__(256) void prep_all(const float* __restrict__ latents,
                                                const float* __restrict__ actions,
                                                const int* __restrict__ rowidx,
                                                const float* __restrict__ W1,
                                                const float* __restrict__ W2,
                                                bf16_t* __restrict__ xs,
                                                bf16_t* __restrict__ w1t,
                                                bf16_t* __restrict__ w2t) {
    int bx = blockIdx.x;
    int tid = threadIdx.x;
    if (bx < PREP_BLOCKS) {
        int idx = bx * 256 + tid;
        int s = idx / 72;
        int col = (idx - s * 72) * 8;
        int g = rowidx[s];
        bf16x8 o;
        if (g < 0) {
            o = (bf16x8){0,0,0,0,0,0,0,0};
        } else {
            const float* src;
            if (col < D_SZ) src = latents + (size_t)g * D_SZ + col;
            else            src = actions + (size_t)g * A_SZ + (col - D_SZ);
            f32x4 v0 = *(const f32x4*)src;
            f32x4 v1 = *(const f32x4*)(src + 4);
            o[0] = (bf16_t)v0[0]; o[1] = (bf16_t)v0[1]; o[2] = (bf16_t)v0[2]; o[3] = (bf16_t)v0[3];
            o[4] = (bf16_t)v1[0]; o[5] = (bf16_t)v1[1]; o[6] = (bf16_t)v1[2]; o[7] = (bf16_t)v1[3];
        }
        *(bf16x8*)(xs + (size_t)s * K1 + col) = o;
        return;
    }
    int tz = bx - PREP_BLOCKS;
    const float* Wp; bf16_t* WTp; int K, N, k0, n0;
    if (tz < TR1_BLOCKS) {
        int p = tz / 144, rem = tz % 144;    // 9 k-tiles x 16 n-tiles
        k0 = (rem / 16) * 64; n0 = (rem % 16) * 64;
        K = K1; N = H_SZ;
        Wp = W1 + (size_t)p * K1 * H_SZ;
        WTp = w1t + (size_t)p * H_SZ * K1;
    } else {
        int u = tz - TR1_BLOCKS;
        int p = u / 128, rem = u % 128;      // 16 k-tiles x 8 n-tiles
        k0 = (rem / 8) * 64; n0 = (rem % 8) * 64;
        K = H_SZ; N = D_SZ;
        Wp = W2 + (size_t)p * H_SZ * D_SZ;
        WTp = w2t + (size_t)p * D_SZ * H_SZ;
    }
    __shared__ float ls[64][65];
#pragma unroll
    for (int e = 0; e < 4; ++e) {
        int idx = e * 256 + tid;
        int kk = idx >> 4, nn = (idx & 15) * 4;
        f32x4 v = *(const f32x4*)&Wp[(size_t)(k0 + kk) * N + n0 + nn];
        ls[kk][nn]     = v[0];
        ls[kk][nn + 1] = v[1];
        ls[kk][nn + 2] = v[2];
        ls[kk][nn + 3] = v[3];
    }
    __syncthreads();
#pragma unroll
    for (int e = 0; e < 2; ++e) {
        int idx = e * 256 + tid;
        int nn = idx >> 3, ks = (idx & 7) * 8;
        bf16x8 o;
#pragma unroll
        for (int q = 0; q < 8; ++q) o[q] = (bf16_t)ls[ks + q][nn];
        *(bf16x8*)&WTp[(size_t)(n0 + nn) * K + k0 + ks] = o;
    }
}

// ---------------- GEMMs: BM=128, 2x2 wave grid, XCD-local n-sweep, BK=64 -----------
// Round-4 post-mortem: all pipes idle at BK=32 -- each 32-k step pays a full
// vmcnt(0)-drain (~900cy) against ~250cy of CU work, and 2.5-4 resident blocks
// stall in near-lockstep. BK=64 halves the drain count (18->9, 32->16 iters):
// two 32-k subtiles staged per barrier pair, identical chunk/swizzle algebra per
// subtile (0 conflicts measured). LDS 32/24 KB keeps residency unchanged.

__global__ __launch_bounds__(256, 3) void gemm1_kernel(
    const bf16_t* __restrict__ xs, const bf16_t* __restrict__ w1t,
    const float* __restrict__ b1, const int* __restrict__ blk_p,
    bf16_t* __restrict__ h) {

    const int b = blockIdx.x;
    const int wid = (b & 7) * (G1_GRID / 8) + (b >> 3);   // XCD-contiguous work id
    const int mb = wid >> 3;
    const int nb = wid & 7;
    const int p = blk_p[mb >> 1];
    if (p < 0) return;
    const int m0 = mb * 128;
    const int n0 = nb * 128;

    constexpr int SUB = 128 * 32;                    // elems per 32-k subtile
    __shared__ __align__(16) bf16_t As[2 * SUB];     // 16 KB
    __shared__ __align__(16) bf16_t Bs[2 * SUB];     // 16 KB

    const int tid = threadIdx.x;
    const int wave = tid >> 6, lane = tid & 63;

    // per subtile hh: A/B each 512 chunks, 8 slots of 64; wave handles slots wave*2+i
    const bf16_t *a_src[2][2], *b_src[2][2];
    bf16_t *a_dst[2][2], *b_dst[2][2];
#pragma unroll
    for (int hh = 0; hh < 2; ++hh)
#pragma unroll
        for (int i = 0; i < 2; ++i) {
            int c = (wave * 2 + i) * 64 + lane;
            int r = c >> 2;
            int kl = (c & 3) ^ ((r >> 1) & 3);
            a_src[hh][i] = xs + (size_t)(m0 + r) * K1 + hh * 32 + kl * 8;
            a_dst[hh][i] = As + hh * SUB + c * 8;
            b_src[hh][i] = w1t + ((size_t)p * H_SZ + n0 + r) * K1 + hh * 32 + kl * 8;
            b_dst[hh][i] = Bs + hh * SUB + c * 8;
        }

    const int l16 = lane & 15, qd = lane >> 4;
    const int swz = (l16 >> 1) & 3;
    const int wr = wave >> 1, wc = wave & 1;   // 2x2 wave grid; wave tile 64x64
    int aoff[4], boff[4];
#pragma unroll
    for (int i = 0; i < 4; ++i) aoff[i] = (wr * 64 + i * 16 + l16) * 32 + ((qd ^ swz) * 8);
#pragma unroll
    for (int j = 0; j < 4; ++j) boff[j] = (wc * 64 + j * 16 + l16) * 32 + ((qd ^ swz) * 8);

    f32x4 acc[4][4];
#pragma unroll
    for (int i = 0; i < 4; ++i)
#pragma unroll
        for (int j = 0; j < 4; ++j)
            acc[i][j] = (f32x4){0.f, 0.f, 0.f, 0.f};

    for (int kt = 0; kt < K1; kt += 64) {
        __syncthreads();   // previous iter's frags consumed
#pragma unroll
        for (int hh = 0; hh < 2; ++hh)
#pragma unroll
            for (int i = 0; i < 2; ++i) {
                glds16(a_src[hh][i] + kt, a_dst[hh][i]);
                glds16(b_src[hh][i] + kt, b_dst[hh][i]);
            }
        __syncthreads();   // staging complete (compiler inserts vmcnt(0))
#pragma unroll
        for (int hh = 0; hh < 2; ++hh) {
            bf16x8 af[4], bfv[4];
#pragma unroll
            for (int i = 0; i < 4; ++i) af[i] = *(const bf16x8*)(As + hh * SUB + aoff[i]);
#pragma unroll
            for (int j = 0; j < 4; ++j) bfv[j] = *(const bf16x8*)(Bs + hh * SUB + boff[j]);
#pragma unroll
            for (int i = 0; i < 4; ++i)
#pragma unroll
                for (int j = 0; j < 4; ++j)
                    acc[i][j] = __builtin_amdgcn_mfma_f32_16x16x32_bf16(af[i], bfv[j], acc[i][j], 0, 0, 0);
        }
    }

    // epilogue: bias + relu -> h (padded sorted layout)
#pragma unroll
    for (int i = 0; i < 4; ++i) {
#pragma unroll
        for (int r = 0; r < 4; ++r) {
            int ml = wr * 64 + i * 16 + qd * 4 + r;     // C/D: row = quad*4 + reg
            size_t row = (size_t)(m0 + ml);
#pragma unroll
            for (int j = 0; j < 4; ++j) {
                int n = n0 + wc * 64 + j * 16 + l16;    // C/D: col = lane&15
                float v = acc[i][j][r] + b1[p * H_SZ + n];
                h[row * H_SZ + n] = (bf16_t)fmaxf(v, 0.f);
            }
        }
    }
}

__global__ __launch_bounds__(256, 4) void gemm2_kernel(
    const bf16_t* __restrict__ h, const bf16_t* __restrict__ w2t,
    const float* __restrict__ b2, const int* __restrict__ blk_p,
    const int* __restrict__ rowidx, float* __restrict__ out) {

    const int b = blockIdx.x;
    const int wid = (b & 7) * (G2_GRID / 8) + (b >> 3);   // XCD-contiguous work id
    const int mb = wid >> 3;
    const int nb = wid & 7;
    const int p = blk_p[mb >> 1];
    if (p < 0) return;
    const int m0 = mb * 128;
    const int n0 = nb * 64;

    constexpr int ASUB = 128 * 32;                   // A subtile elems
    constexpr int BSUB = 64 * 32;                    // B subtile elems
    __shared__ __align__(16) bf16_t As[2 * ASUB];    // 16 KB
    __shared__ __align__(16) bf16_t Bs[2 * BSUB];    // 8 KB

    const int tid = threadIdx.x;
    const int wave = tid >> 6, lane = tid & 63;

    // A: per subtile 512 chunks, 8 slots; wave handles slots wave*2+i
    const bf16_t *a_src[2][2]; bf16_t *a_dst[2][2];
#pragma unroll
    for (int hh = 0; hh < 2; ++hh)
#pragma unroll
        for (int i = 0; i < 2; ++i) {
            int c = (wave * 2 + i) * 64 + lane;
            int r = c >> 2;
            int kl = (c & 3) ^ ((r >> 1) & 3);
            a_src[hh][i] = h + (size_t)(m0 + r) * H_SZ + hh * 32 + kl * 8;
            a_dst[hh][i] = As + hh * ASUB + c * 8;
        }
    // B: per subtile 256 chunks, 4 slots; wave handles slot `wave`
    const bf16_t *b_src[2]; bf16_t *b_dst[2];
#pragma unroll
    for (int hh = 0; hh < 2; ++hh) {
        int c = wave * 64 + lane;
        int r = c >> 2;
        int kl = (c & 3) ^ ((r >> 1) & 3);
        b_src[hh] = w2t + ((size_t)p * D_SZ + n0 + r) * H_SZ + hh * 32 + kl * 8;
        b_dst[hh] = Bs + hh * BSUB + c * 8;
    }

    const int l16 = lane & 15, qd = lane >> 4;
    const int swz = (l16 >> 1) & 3;
    const int wr = wave >> 1, wc = wave & 1;   // 2x2 wave grid; wave tile 64x32
    int aoff[4], boff[2];
#pragma unroll
    for (int i = 0; i < 4; ++i) aoff[i] = (wr * 64 + i * 16 + l16) * 32 + ((qd ^ swz) * 8);
#pragma unroll
    for (int j = 0; j < 2; ++j) boff[j] = (wc * 32 + j * 16 + l16) * 32 + ((qd ^ swz) * 8);

    f32x4 acc[4][2];
#pragma unroll
    for (int i = 0; i < 4; ++i)
#pragma unroll
        for (int j = 0; j < 2; ++j)
            acc[i][j] = (f32x4){0.f, 0.f, 0.f, 0.f};

    for (int kt = 0; kt < H_SZ; kt += 64) {
        __syncthreads();
#pragma unroll
        for (int hh = 0; hh < 2; ++hh) {
#pragma unroll
            for (int i = 0; i < 2; ++i) glds16(a_src[hh][i] + kt, a_dst[hh][i]);
            glds16(b_src[hh] + kt, b_dst[hh]);
        }
        __syncthreads();
#pragma unroll
        for (int hh = 0; hh < 2; ++hh) {
            bf16x8 af[4], bfv[2];
#pragma unroll
            for (int i = 0; i < 4; ++i) af[i] = *(const bf16x8*)(As + hh * ASUB + aoff[i]);
#pragma unroll
            for (int j = 0; j < 2; ++j) bfv[j] = *(const bf16x8*)(Bs + hh * BSUB + boff[j]);
#pragma unroll
            for (int i = 0; i < 4; ++i)
#pragma unroll
                for (int j = 0; j < 2; ++j)
                    acc[i][j] = __builtin_amdgcn_mfma_f32_16x16x32_bf16(af[i], bfv[j], acc[i][j], 0, 0, 0);
        }
    }

    // epilogue: bias, scatter to original rows; pad rows masked
#pragma unroll
    for (int i = 0; i < 4; ++i) {
#pragma unroll
        for (int r = 0; r < 4; ++r) {
            int ml = wr * 64 + i * 16 + qd * 4 + r;
            int g = rowidx[m0 + ml];
            if (g >= 0) {
                size_t orow = (size_t)g * D_SZ;
#pragma unroll
                for (int j = 0; j < 2; ++j) {
                    int n = n0 + wc * 32 + j * 16 + l16;
                    out[orow + n] = acc[i][j][r] + b2[p * D_SZ + n];
                }
            }
        }
    }
}

// ---------------- launch ----------------

extern "C" void kernel_launch(void* const* d_in, const int* in_sizes, int n_in,
                              void* d_out, int out_size, void* d_ws, size_t ws_size,
                              hipStream_t stream) {
    const float* latents = (const float*)d_in[0];
    const float* actions = (const float*)d_in[1];
    const int*   pol     = (const int*)d_in[2];
    const float* W1      = (const float*)d_in[3];
    const float* b1      = (const float*)d_in[4];
    const float* W2      = (const float*)d_in[5];
    const float* b2      = (const float*)d_in[6];
    float* out = (float*)d_out;

    char* ws = (char*)d_ws;
    int* counts    = (int*)ws;
    int* cursors   = counts + P_SZ;
    int* blk_p     = cursors + P_SZ;
    int* blockhist = blk_p + MB_MAX;
    int* rowidx    = blockhist + NSEG * P_SZ;
    size_t pos = ((size_t)(2 * P_SZ + MB_MAX + NSEG * P_SZ + BPAD) * sizeof(int) + 255) & ~(size_t)255;
    bf16_t* xs  = (bf16_t*)(ws + pos);  pos += (size_t)BPAD * K1 * 2;
    bf16_t* hbuf= (bf16_t*)(ws + pos);  pos += (size_t)BPAD * H_SZ * 2;
    bf16_t* w1t = (bf16_t*)(ws + pos);  pos += (size_t)P_SZ * H_SZ * K1 * 2;
    bf16_t* w2t = (bf16_t*)(ws + pos);  pos += (size_t)P_SZ * D_SZ * H_SZ * 2;

    hist_block<<<NSEG, 256, 0, stream>>>(pol, blockhist, rowidx);
    prefix_kernel<<<1, 256, 0, stream>>>(blockhist, counts, cursors, blk_p);
    scatter_agg<<<NSEG, 256, 0, stream>>>(pol, cursors, rowidx);
    prep_all<<<PREP_BLOCKS + TR1_BLOCKS + TR2_BLOCKS, 256, 0, stream>>>(
        latents, actions, rowidx, W1, W2, xs, w1t, w2t);
    gemm1_kernel<<<G1_GRID, 256, 0, stream>>>(xs, w1t, b1, blk_p, hbuf);
    gemm2_kernel<<<G2_GRID, 256, 0, stream>>>(hbuf, w2t, b2, blk_p, rowidx, out);
}